// Round 7
// baseline (970.482 us; speedup 1.0000x reference)
//
#include <hip/hip_runtime.h>

#define T_LEN 2048
#define HID   25
#define LOG2E 1.4426950408889634f

// may_alias vector for the LDS h-row readback (written as scalar float):
// without it, TBAA licenses hoisting the read above the publish (R3/R7 bug).
// R18 relies on alias deps (no asm fences): the publish store and the vf4
// readback target the SAME hbuf object at runtime offsets, so BasicAA keeps
// store->load order. Same-wave DS ops execute in order on HW. Fence removal
// was correctness-proven by R17 (passed, absmax 1.953e-3).
typedef float vf4 __attribute__((vector_size(16), may_alias));
typedef float f2  __attribute__((ext_vector_type(2)));

__device__ __forceinline__ float fast_rcp(float x) { return __builtin_amdgcn_rcpf(x); }
__device__ __forceinline__ float fast_exp2(float x) { return __builtin_amdgcn_exp2f(x); }

// R18 = champion R11 per-chain step x 2 pipeline stages in one wave.
//
// Evidence chain: R14 (gate-split, 2 waves/SIMD) -- sibling wave hid nothing.
// R15 (phase skew) -- exactly neutral: HW co-scheduling won't hide this
// latency. R16/R17 (2-chain in-stream pipeline on the gate-split step) -- no
// overlap with or without fences: the step's __shfl_xor (ds_bpermute) needs
// lgkmcnt(0) mid-step, and in-order LDS completion means that wait DRAINS the
// other chain's prefetched readback every step. The gate-split structure is
// un-pipelineable.
//
// R11's step has NO shuffle: lane u owns all 4 gate rows of unit u; the only
// DS ops are tail publish (2 ds_write) + readback (6 ds_read_b128 + 1 b32).
// So: each wave runs FOUR chains = two R11-style stages (P: 2 half-wave
// chains, Q: 2 more), alternating in program order. Stage P's readback has
// stage Q's entire step (~430 issue cyc) between issue and first use -- no
// drain points in between; compiler emits counted lgkmcnt (as in m97). The
// two y-phases merge into one branch so P+Q ops form a single basic block.
//
// No-overlap worst case = 2*(430+210) cyc per superstep of 4 chains
// = 320 cyc/chain-step = exactly the champion -- downside bounded at a tie.
//
// Numerics: step body is the champion's verbatim (same (k,k+12) pk-pairing,
// same acc.x + fmaf(h24,...) tail, exp2-domain activations, same c/h/y
// order) -> absmax must stay exactly 1.953e-3.
//
// Launch: 256 blocks x 128 threads = 512 waves, 4 chains each = 2048 chains.
// All 256 CUs get one block (2 waves on 2 SIMDs); waves_per_eu(1,1) caps at
// 1 wave/SIMD -> full VGPR budget (R8 lesson). DS pressure/CU halves vs
// champion (2 waves x 14 DS-ops per ~900cyc vs 4 waves x 7 per 640).

__global__ __attribute__((amdgpu_flat_work_group_size(128, 128),
                          amdgpu_waves_per_eu(1, 1)))
void lstm_fused(
    const float* __restrict__ x,        // [B, T, 1]
    const float* __restrict__ w_ih,     // [100, 1]
    const float* __restrict__ w_hh,     // [100, 25]
    const float* __restrict__ b_ih,     // [100]
    const float* __restrict__ b_hh,     // [100]
    const float* __restrict__ w_dense,  // [1, 25]
    const float* __restrict__ b_dense,  // [1]
    float* __restrict__ out)            // [B, T, 1]
{
    const int tid  = threadIdx.x;
    const int l    = tid & 63;           // lane in wave
    const int u    = l & 31;             // hidden unit / t'-slot owned by lane
    const int cbh  = l >> 5;             // half-wave index: 0 or 1
    const int w    = tid >> 6;           // wave in block: 0 or 1
    const int base = (blockIdx.x * 2 + w) * 4;  // 4 chains per wave
    const int chP  = base + cbh;         // stage-P chain for this lane
    const int chQ  = base + 2 + cbh;     // stage-Q chain for this lane
    const bool act = u < HID;

    // Per wave, 4 chain rows of 32 floats (interleaved bijection, see below).
    __shared__ __align__(16) float hbuf[2][4][32];
    // h history for batched y: per chain, 32 steps x 33 floats (stride 33:
    // lane-strided y reads conflict-free).
    __shared__ float hist[2][4][32][33];

    const float si = -LOG2E, sg = 2.f * LOG2E;

    // ---- recurrent weights as (k, k+12) pairs, pre-scaled into exp2 domain
    // (champion's layout: lane u owns ALL FOUR gate rows of unit u; weights
    // shared by all 4 chains of the wave) ----
    f2 wI2[12], wF2[12], wG2[12], wO2[12];
#pragma unroll
    for (int m = 0; m < 12; ++m) {
        wI2[m] = act ? f2{si * w_hh[u * HID + m],             si * w_hh[u * HID + m + 12]}             : f2{0.f, 0.f};
        wF2[m] = act ? f2{si * w_hh[(HID + u) * HID + m],     si * w_hh[(HID + u) * HID + m + 12]}     : f2{0.f, 0.f};
        wG2[m] = act ? f2{sg * w_hh[(2 * HID + u) * HID + m], sg * w_hh[(2 * HID + u) * HID + m + 12]} : f2{0.f, 0.f};
        wO2[m] = act ? f2{si * w_hh[(3 * HID + u) * HID + m], si * w_hh[(3 * HID + u) * HID + m + 12]} : f2{0.f, 0.f};
    }
    const float wI24 = act ? si * w_hh[u * HID + 24]             : 0.f;
    const float wF24 = act ? si * w_hh[(HID + u) * HID + 24]     : 0.f;
    const float wG24 = act ? sg * w_hh[(2 * HID + u) * HID + 24] : 0.f;
    const float wO24 = act ? si * w_hh[(3 * HID + u) * HID + 24] : 0.f;

    const float bI  = act ? si * (b_ih[u] + b_hh[u]) : 0.f;
    const float bF  = act ? si * (b_ih[HID + u] + b_hh[HID + u]) : 0.f;
    const float bG  = act ? sg * (b_ih[2 * HID + u] + b_hh[2 * HID + u]) : 0.f;
    const float bO  = act ? si * (b_ih[3 * HID + u] + b_hh[3 * HID + u]) : 0.f;
    const float wxI = act ? si * w_ih[u] : 0.f;
    const float wxF = act ? si * w_ih[HID + u] : 0.f;
    const float wxG = act ? sg * w_ih[2 * HID + u] : 0.f;
    const float wxO = act ? si * w_ih[3 * HID + u] : 0.f;
    const float bd  = b_dense[0];

    // dense weights (wave-uniform loads -> SGPRs)
    float wdv[HID];
#pragma unroll
    for (int i = 0; i < HID; ++i) wdv[i] = w_dense[i];

    // h0 = 0 (all 4 rows of this wave)
    hbuf[w][cbh][u]     = 0.f;
    hbuf[w][2 + cbh][u] = 0.f;

    // interleaved publish slot within the chain's row: bijection, 2 lanes/bank
    const int slot = (u < 12) ? 2 * u : (u < 24) ? 2 * u - 23 : u;
    float* hwrP = &hbuf[w][cbh][slot];
    float* hwrQ = &hbuf[w][2 + cbh][slot];
    const vf4* r4P = (const vf4*)&hbuf[w][cbh][0];
    const vf4* r4Q = (const vf4*)&hbuf[w][2 + cbh][0];
    const float* hbFP = &hbuf[w][cbh][0];
    const float* hbFQ = &hbuf[w][2 + cbh][0];
    float (*histP)[33] = hist[w][cbh];
    float (*histQ)[33] = hist[w][2 + cbh];

    const float4* __restrict__ xpP = (const float4*)(x + (size_t)chP * T_LEN);
    const float4* __restrict__ xpQ = (const float4*)(x + (size_t)chQ * T_LEN);
    float* __restrict__ orowP = out + (size_t)chP * T_LEN;
    float* __restrict__ orowQ = out + (size_t)chQ * T_LEN;

    // h state as 12 register-aligned pairs (h_m, h_{m+12}) + h24, per stage
    f2 hpP[12], hpQ[12];
#pragma unroll
    for (int m = 0; m < 12; ++m) { hpP[m] = f2{0.f, 0.f}; hpQ[m] = f2{0.f, 0.f}; }
    float h24P = 0.f, h24Q = 0.f;
    float cP = 0.f, cQ = 0.f;

    float4 xcP = xpP[0], xcQ = xpQ[0];

    // One champion-R11 step for one stage (verbatim arithmetic; no fences).
    auto step = [&](f2* hp, float& h24, float& c, float xv, int t,
                    float* hwr, const vf4* r4, const float* hbF,
                    float (*histc)[33]) {
        f2 accI = f2{fmaf(xv, wxI, bI), 0.f};
        f2 accF = f2{fmaf(xv, wxF, bF), 0.f};
        f2 accG = f2{fmaf(xv, wxG, bG), 0.f};
        f2 accO = f2{fmaf(xv, wxO, bO), 0.f};
#pragma unroll
        for (int m = 0; m < 12; ++m) {
            const f2 h = hp[m];
            accI = __builtin_elementwise_fma(h, wI2[m], accI);
            accF = __builtin_elementwise_fma(h, wF2[m], accF);
            accG = __builtin_elementwise_fma(h, wG2[m], accG);
            accO = __builtin_elementwise_fma(h, wO2[m], accO);
        }
        const float aI = accI.x + fmaf(h24, wI24, accI.y);
        const float aF = accF.x + fmaf(h24, wF24, accF.y);
        const float aG = accG.x + fmaf(h24, wG24, accG.y);
        const float aO = accO.x + fmaf(h24, wO24, accO.y);

        const float sI = fast_rcp(1.f + fast_exp2(aI));          // sig(i)
        const float sF = fast_rcp(1.f + fast_exp2(aF));          // sig(f)
        const float sO = fast_rcp(1.f + fast_exp2(aO));          // sig(o)
        const float tG = fmaf(-2.f, fast_rcp(1.f + fast_exp2(aG)), 1.f); // tanh(g)

        c = fmaf(sF, c, sI * tG);
        const float tC = fmaf(-2.f, fast_rcp(1.f + fast_exp2(2.f * LOG2E * c)), 1.f);
        const float hn = sO * tC;

        // ---- publish -> readback; order pinned by same-object alias deps;
        // same-wave DS ops execute in order on HW ----
        *hwr = hn;                       // interleaved slot (bijection)
        histc[t & 31][u] = hn;           // all 32 lanes, slots 0..31 of 33
        {
            vf4 a0 = r4[0], a1 = r4[1], a2 = r4[2];
            vf4 a3 = r4[3], a4 = r4[4], a5 = r4[5];
            hp[0]  = f2{a0[0], a0[1]}; hp[1]  = f2{a0[2], a0[3]};
            hp[2]  = f2{a1[0], a1[1]}; hp[3]  = f2{a1[2], a1[3]};
            hp[4]  = f2{a2[0], a2[1]}; hp[5]  = f2{a2[2], a2[3]};
            hp[6]  = f2{a3[0], a3[1]}; hp[7]  = f2{a3[2], a3[3]};
            hp[8]  = f2{a4[0], a4[1]}; hp[9]  = f2{a4[2], a4[3]};
            hp[10] = f2{a5[0], a5[1]}; hp[11] = f2{a5[2], a5[3]};
            h24 = hbF[24];
        }
    };

    for (int it = 0; it < T_LEN / 4; ++it) {
        const int nx = (it + 1 < T_LEN / 4) ? it + 1 : it;
        float4 xnP = xpP[nx], xnQ = xpQ[nx];   // issued ~4 steps ahead of use
        float xsP[4] = {xcP.x, xcP.y, xcP.z, xcP.w};
        float xsQ[4] = {xcQ.x, xcQ.y, xcQ.z, xcQ.w};

#pragma unroll
        for (int s = 0; s < 4; ++s) {
            const int t = 4 * it + s;
            // Stage P's readback is covered by stage Q's full step; stage Q's
            // readback by the next s-iteration's stage P (one basic block --
            // the y-branch below is shared by both stages).
            step(hpP, h24P, cP, xsP[s], t, hwrP, r4P, hbFP, histP);
            step(hpQ, h24Q, cQ, xsQ[s], t, hwrQ, r4Q, hbFQ, histQ);

            // batched y: every 32 steps lane l computes y[t0+u] for its
            // half-wave chain of each stage (full 25-sum, stride-33 reads
            // conflict-free), 128 B coalesced stores per chain.
            if ((t & 31) == 31) {
                const float* hrP = &histP[u][0];
                const float* hrQ = &histQ[u][0];
                float ysP = 0.f, ysQ = 0.f;
#pragma unroll
                for (int i = 0; i < HID; ++i) {
                    ysP = fmaf(hrP[i], wdv[i], ysP);
                    ysQ = fmaf(hrQ[i], wdv[i], ysQ);
                }
                orowP[(t & ~31) + u] = ysP + bd;
                orowQ[(t & ~31) + u] = ysQ + bd;
            }
        }
        xcP = xnP;
        xcQ = xnQ;
    }
}

extern "C" void kernel_launch(void* const* d_in, const int* in_sizes, int n_in,
                              void* d_out, int out_size, void* d_ws, size_t ws_size,
                              hipStream_t stream) {
    const float* x       = (const float*)d_in[0];
    const float* w_ih    = (const float*)d_in[1];
    const float* w_hh    = (const float*)d_in[2];
    const float* b_ih    = (const float*)d_in[3];
    const float* b_hh    = (const float*)d_in[4];
    const float* w_dense = (const float*)d_in[5];
    const float* b_dense = (const float*)d_in[6];
    float* out = (float*)d_out;

    // 2048 chains, four per wave (2 half-wave chains x 2 pipeline stages):
    // 256 blocks x 128 threads = 512 waves; 1 block/CU, 2 waves on 2 SIMDs,
    // capped at 1 wave/SIMD by waves_per_eu(1,1).
    lstm_fused<<<dim3(256), dim3(128), 0, stream>>>(x, w_ih, w_hh, b_ih, b_hh,
                                                    w_dense, b_dense, out);
}